// Round 19
// baseline (171.860 us; speedup 1.0000x reference)
//
#include <hip/hip_runtime.h>
#include <hip/hip_bf16.h>
#include <math.h>

#define NNODES 10000
#define NEDGES 80000
#define FDIM   1024
#define BGR    32
#define LLEN   800
#define CCH    16
#define DDIM   128
#define NPAD2  10240   // 80 * 128
#define NE_BLK 625     // 2*NEDGES/256

typedef __attribute__((ext_vector_type(4))) _Float16 f16x4;
typedef __attribute__((ext_vector_type(8))) _Float16 f16x8;
typedef __attribute__((ext_vector_type(4))) float f32x4;
typedef __attribute__((ext_vector_type(2))) float f32x2;
typedef __attribute__((ext_vector_type(2))) long long2v;

__device__ __forceinline__ float lrelu(float v){ return v > 0.0f ? v : 0.01f*v; }

// ---- edge in-degree counts only; grid 625, blk 256 ----
__global__ __launch_bounds__(256) void k_deg(const int* __restrict__ ei0, const int* __restrict__ ei1,
                                             int* __restrict__ cnt){
  int i = blockIdx.x*256 + threadIdx.x;
  int br = i >= NEDGES;
  int e  = br ? i - NEDGES : i;
  const int* ei = br ? ei1 : ei0;
  atomicAdd(&cnt[br*NNODES + ei[NEDGES + e]], 1);
}

// ---- per-branch exclusive scan + dinv + bstart; grid=2 blocks of 1024 ----
__global__ __launch_bounds__(1024) void k_scan(const int* __restrict__ cnt, int* __restrict__ rowstart,
                                               float* __restrict__ dinv,
                                               const int* __restrict__ batch0,
                                               const int* __restrict__ batch1,
                                               int* __restrict__ bstart_){
  __shared__ int part[1024];
  const int br = blockIdx.x;
  const int* c = cnt + br*NNODES;
  int* rs = rowstart + br*(NNODES+1);
  float* dv = dinv + br*NNODES;
  const int* batch = br ? batch1 : batch0;
  int* bstart = bstart_ + br*(BGR+1);
  const int t = threadIdx.x;
  const int base = t*10;
  int local[10];
  int s = 0;
  #pragma unroll
  for (int i = 0; i < 10; ++i){
    int v = (base+i < NNODES) ? c[base+i] : 0;
    local[i] = s; s += v;
    if (base+i < NNODES) dv[base+i] = rsqrtf((float)v + 1.0f);
  }
  part[t] = s;
  __syncthreads();
  for (int off = 1; off < 1024; off <<= 1){
    int v = (t >= off) ? part[t-off] : 0;
    __syncthreads();
    part[t] += v;
    __syncthreads();
  }
  const int prev = (t == 0) ? 0 : part[t-1];
  #pragma unroll
  for (int i = 0; i < 10; ++i)
    if (base+i < NNODES) rs[base+i] = prev + local[i];
  if (t == 0) rs[NNODES] = NEDGES;
  for (int i = base; i < base+10 && i < NNODES; ++i){
    int b = batch[i];
    if (i == 0){ for (int bb = 0; bb <= b; ++bb) bstart[bb] = 0; }
    else {
      int pb = batch[i-1];
      if (b != pb) for (int bb = pb+1; bb <= b; ++bb) bstart[bb] = i;
    }
    if (i == NNODES-1){ for (int bb = b+1; bb <= BGR; ++bb) bstart[bb] = NNODES; }
  }
}

// ---- wide misc: CSR fill || cvtX(fp8) || cvtW(fp8, unit-permuted) || masif ----
__global__ __launch_bounds__(256) void k_misc(const int* __restrict__ ei0, const int* __restrict__ ei1,
                                              const int* __restrict__ rowstart,
                                              int* __restrict__ cursor, int* __restrict__ csr,
                                              const float* __restrict__ x0, const float* __restrict__ x1,
                                              const float* __restrict__ dinv,
                                              unsigned char* __restrict__ xs8,
                                              const float* __restrict__ W0, const float* __restrict__ W1,
                                              unsigned char* __restrict__ Wt8,
                                              const float* __restrict__ ms1, const float* __restrict__ mf1,
                                              const float* __restrict__ ms2, const float* __restrict__ mf2,
                                              const float* __restrict__ sw1, const float* __restrict__ sb1,
                                              const float* __restrict__ fw1, const float* __restrict__ fb1,
                                              const float* __restrict__ sw2, const float* __restrict__ sb2,
                                              const float* __restrict__ fw2, const float* __restrict__ fb2,
                                              const float* __restrict__ Wm1, const float* __restrict__ bm1,
                                              const float* __restrict__ Wm2, const float* __restrict__ bm2,
                                              float* __restrict__ m12){
  __shared__ float tl[32][33];
  __shared__ float sf[LLEN];
  __shared__ float w80[80];
  const int bx = blockIdx.x, t = threadIdx.x;
  if (bx < NE_BLK){
    // CSR fill
    const int i = bx*256 + t;
    const int br = i >= NEDGES;
    const int e  = br ? i - NEDGES : i;
    const int* ei = br ? ei1 : ei0;
    const int r = ei[e], c = ei[NEDGES + e];
    const int pos = atomicAdd(&cursor[br*NNODES + c], 1);
    csr[br*NEDGES + rowstart[br*(NNODES+1) + c] + pos] = r;
  } else if (bx < NE_BLK + 2*NNODES){
    // cvtX: xs8[row] = fp8(dinv[row] * x[row]); LINEAR layout (gather input)
    const int idx = bx - NE_BLK;              // 0..19999
    const int br = idx >= NNODES;
    const int row = br ? idx - NNODES : idx;
    const float* x = (br ? x1 : x0) + (size_t)row*FDIM;
    unsigned char* o = xs8 + ((size_t)br*NNODES + row)*FDIM;
    const int f = t*4;
    const float d = dinv[br*NNODES + row];
    const float4 v = *(const float4*)(x + f);
    int p = __builtin_amdgcn_cvt_pk_fp8_f32(v.x*d, v.y*d, 0, false);
    p = __builtin_amdgcn_cvt_pk_fp8_f32(v.z*d, v.w*d, p, true);
    *(int*)(o + f) = p;
  } else if (bx < NE_BLK + 2*NNODES + 2048){
    // cvtW transpose + fp8 cast, UNIT-PERMUTED within each 64B k-group:
    // 8B unit u -> position 2*(u&3)+(u>>2); phys slot p holds units {p, p+4}.
    const int idx = bx - NE_BLK - 2*NNODES;
    const int br = idx >> 10, tile = idx & 1023;
    const float* W = br ? W1 : W0;
    unsigned char* Wo = Wt8 + (size_t)br*FDIM*FDIM;
    const int k0 = (tile >> 5)*32, n0 = (tile & 31)*32;
    const int r = t >> 3, c4 = (t & 7)*4;
    const float4 v = *(const float4*)(W + (size_t)(k0+r)*FDIM + n0 + c4);
    tl[r][c4] = v.x; tl[r][c4+1] = v.y; tl[r][c4+2] = v.z; tl[r][c4+3] = v.w;
    __syncthreads();
    int p = __builtin_amdgcn_cvt_pk_fp8_f32(tl[c4  ][r], tl[c4+1][r], 0, false);
    p = __builtin_amdgcn_cvt_pk_fp8_f32(tl[c4+2][r], tl[c4+3][r], p, true);
    const int L = k0 + c4;                           // logical k-byte
    const int g = L >> 6, u = (L >> 3) & 7, h = (L >> 2) & 1;
    const int Lp = g*64 + (2*(u&3) + (u>>2))*8 + h*4;
    *(int*)(Wo + (size_t)(n0+r)*FDIM + Lp) = p;
  } else {
    // masif
    const int idx = bx - NE_BLK - 2*NNODES - 2048;   // 0..63
    const int br = idx >> 5, b = idx & 31;
    const float* ms = br ? ms2 : ms1;
    const float* mf = br ? mf2 : mf1;
    const float swv = (br ? sw2 : sw1)[0], sbv = (br ? sb2 : sb1)[0];
    const float fwv = (br ? fw2 : fw1)[0], fbv = (br ? fb2 : fb1)[0];
    const float* Wm = br ? Wm2 : Wm1;
    const float* bm = br ? bm2 : bm1;
    for (int l = t; l < LLEN; l += 256){
      float sm = 0.f, fm = 0.f;
      for (int c = 0; c < CCH; ++c){
        sm += ms[((size_t)b*CCH + c)*LLEN + l];
        fm += mf[((size_t)b*CCH + c)*LLEN + l];
      }
      sm = fmaxf(sm*(1.0f/16.0f)*swv + sbv, 0.f);
      fm = fmaxf(fm*(1.0f/16.0f)*fwv + fbv, 0.f);
      sf[l] = sm + fm;
    }
    __syncthreads();
    if (t < 80){
      float a = 0.f;
      for (int j = 0; j < 10; ++j) a += sf[t*10 + j];
      w80[t] = a * 0.05f;
    }
    __syncthreads();
    if (t < 64){
      float acc = bm[t];
      for (int k = 0; k < 80; ++k) acc += w80[k] * Wm[k*64 + t];
      m12[((size_t)br*BGR + b)*64 + t] = acc;
    }
  }
}

// ---- gather one node (fp8 in linear, fp8 out unit-permuted) ----
__device__ __forceinline__ void gather_body(int n, int br, int lt,
    const unsigned char* __restrict__ xs8_, const int* __restrict__ rowstart_,
    const int* __restrict__ csr_, const float* __restrict__ dinv_,
    unsigned char* __restrict__ xa8_)
{
  const unsigned char* xs8 = xs8_ + (size_t)br*NNODES*FDIM;
  const int* rowstart = rowstart_ + br*(NNODES+1);
  const int* csr = csr_ + br*NEDGES;
  const float* dinv = dinv_ + br*NNODES;
  unsigned char* xa8 = xa8_ + (size_t)br*NPAD2*FDIM;

  const int f = lt*8;                               // logical k-range read
  const int g = lt >> 3, u = lt & 7;                // permuted write position
  const int fp = g*64 + (2*(u&3) + (u>>2))*8;
  unsigned char* op = xa8 + (size_t)n*FDIM + fp;
  if (n >= NNODES){
    *(long*)op = 0L;
    return;
  }
  const int s0 = rowstart[n], s1 = rowstart[n+1];
  float a0=0,a1=0,a2=0,a3=0,a4=0,a5=0,a6=0,a7=0;
  auto addrow = [&](uint2 q){
    f32x2 w0 = __builtin_amdgcn_cvt_pk_f32_fp8((int)q.x, false);
    f32x2 w1 = __builtin_amdgcn_cvt_pk_f32_fp8((int)q.x, true);
    f32x2 w2 = __builtin_amdgcn_cvt_pk_f32_fp8((int)q.y, false);
    f32x2 w3 = __builtin_amdgcn_cvt_pk_f32_fp8((int)q.y, true);
    a0 += w0[0]; a1 += w0[1]; a2 += w1[0]; a3 += w1[1];
    a4 += w2[0]; a5 += w2[1]; a6 += w3[0]; a7 += w3[1];
  };
  addrow(*(const uint2*)(xs8 + (size_t)n*FDIM + f));   // self-loop
  int i = s0;
  for (; i + 4 <= s1; i += 4){
    const int r0 = csr[i], r1 = csr[i+1], r2 = csr[i+2], r3 = csr[i+3];
    const uint2 q0 = *(const uint2*)(xs8 + (size_t)r0*FDIM + f);
    const uint2 q1 = *(const uint2*)(xs8 + (size_t)r1*FDIM + f);
    const uint2 q2 = *(const uint2*)(xs8 + (size_t)r2*FDIM + f);
    const uint2 q3 = *(const uint2*)(xs8 + (size_t)r3*FDIM + f);
    addrow(q0); addrow(q1); addrow(q2); addrow(q3);
  }
  for (; i < s1; ++i){
    addrow(*(const uint2*)(xs8 + (size_t)csr[i]*FDIM + f));
  }
  const float d = dinv[n];
  uint2 o;
  int p0 = __builtin_amdgcn_cvt_pk_fp8_f32(a0*d, a1*d, 0, false);
  p0 = __builtin_amdgcn_cvt_pk_fp8_f32(a2*d, a3*d, p0, true);
  int p1 = __builtin_amdgcn_cvt_pk_fp8_f32(a4*d, a5*d, 0, false);
  p1 = __builtin_amdgcn_cvt_pk_fp8_f32(a6*d, a7*d, p1, true);
  o.x = (unsigned)p0; o.y = (unsigned)p1;
  *(uint2*)op = o;
}

// ---- fp8 GEMM tile + fused pooling body (R18-proven). 640 tiles per branch ----
__device__ __forceinline__ void gemm_pool_tile(int id, int br, char* smem,
    const unsigned char* __restrict__ A_, const unsigned char* __restrict__ Bt_,
    const float* __restrict__ bg0, const float* __restrict__ bg1,
    const int* __restrict__ bstart_, float* __restrict__ pool_)
{
  const int w   = (id & 7)*80 + (id >> 3);    // per-branch XCD-local bijection (640=8*80)
  const int col = w & 7;
  const int row = w >> 3;                     // 0..79

  const unsigned char* A  = A_  + (size_t)br*NPAD2*FDIM;
  const unsigned char* Bt = Bt_ + (size_t)br*FDIM*FDIM;
  const float* bg = br ? bg1 : bg0;
  const int* bstart = bstart_ + br*(BGR+1);
  float* pool = pool_ + br*BGR*FDIM;

  const int row0 = row*128, col0 = col*128;
  const int tid  = threadIdx.x;
  const int lane = tid & 63, wave = tid >> 6;
  const int wm = wave >> 1, wn = wave & 1;
  const int lr = lane >> 2;       // 0..15 row within 16-row staging group
  const int ls = lane & 3;        // linear 16B slot within 64B row

  f32x4 acc[4][4] = {};

  auto stage = [&](int buf, int k0){
    char* Asb = smem + buf*8192;
    char* Bsb = smem + 16384 + buf*8192;
    #pragma unroll
    for (int j = 0; j < 2; ++j){
      const int r0 = wave*32 + j*16;
      const int ra = r0 + lr;
      const int sa = ls ^ ((ra >> 1) & 3);    // pre-swizzled 16B slot
      __builtin_amdgcn_global_load_lds(
        (const __attribute__((address_space(1))) void*)(A + (size_t)(row0+ra)*FDIM + k0 + sa*16),
        (__attribute__((address_space(3))) void*)(Asb + r0*64), 16, 0, 0);
      __builtin_amdgcn_global_load_lds(
        (const __attribute__((address_space(1))) void*)(Bt + (size_t)(col0+ra)*FDIM + k0 + sa*16),
        (__attribute__((address_space(3))) void*)(Bsb + r0*64), 16, 0, 0);
    }
  };

  auto compute = [&](int buf){
    const char* Asb = smem + buf*8192;
    const char* Bsb = smem + 16384 + buf*8192;
    long2v af[4], bf[4];
    const int s = lane >> 4;        // 0..3 = phys slot this lane consumes
    #pragma unroll
    for (int i = 0; i < 4; ++i){
      const int rA = wm*64 + i*16 + (lane & 15);
      af[i] = *(const long2v*)(Asb + rA*64 + ((s ^ ((rA>>1)&3))<<4));
      const int rB = wn*64 + i*16 + (lane & 15);
      bf[i] = *(const long2v*)(Bsb + rB*64 + ((s ^ ((rB>>1)&3))<<4));
    }
    #pragma unroll
    for (int mi = 0; mi < 4; ++mi)
      #pragma unroll
      for (int ni = 0; ni < 4; ++ni){
        acc[mi][ni] = __builtin_amdgcn_mfma_f32_16x16x32_fp8_fp8(af[mi][0], bf[ni][0], acc[mi][ni], 0, 0, 0);
        acc[mi][ni] = __builtin_amdgcn_mfma_f32_16x16x32_fp8_fp8(af[mi][1], bf[ni][1], acc[mi][ni], 0, 0, 0);
      }
  };

  stage(0, 0);                                 // 4 loads in flight
  #pragma unroll 2
  for (int ks = 0; ks < 16; ++ks){
    if (ks < 15){
      stage((ks+1)&1, (ks+1)*64);              // +4 -> 8 in flight
      asm volatile("s_waitcnt vmcnt(4)" ::: "memory");   // current tile landed
    } else {
      asm volatile("s_waitcnt vmcnt(0)" ::: "memory");
    }
    __builtin_amdgcn_s_barrier();              // next tile's loads stay in flight
    compute(ks&1);
    __builtin_amdgcn_s_barrier();              // reads done before overwrite
  }
  __syncthreads();   // drain before scratch overwrite

  // write output tile (f16, post bias+lrelu; 0 for pad rows) into 32KB scratch
  _Float16* sc = (_Float16*)smem;
  float bcol[4];
  #pragma unroll
  for (int ni = 0; ni < 4; ++ni) bcol[ni] = bg[col0 + wn*64 + ni*16 + (lane & 15)];
  #pragma unroll
  for (int mi = 0; mi < 4; ++mi){
    #pragma unroll
    for (int j = 0; j < 4; ++j){
      const int lrow = wm*64 + mi*16 + (lane>>4)*4 + j;
      const int valid = (row0 + lrow) < NNODES;
      #pragma unroll
      for (int ni = 0; ni < 4; ++ni){
        const int lcol = wn*64 + ni*16 + (lane & 15);
        sc[lrow*128 + lcol] = valid ? (_Float16)lrelu(acc[mi][ni][j] + bcol[ni]) : (_Float16)0.f;
      }
    }
  }
  __syncthreads();

  // per-column batch-segment sums: thread t owns col c = t&127, half h = t>>7
  {
    const int c = tid & 127, h = tid >> 7;
    const int base = row0 + h*64;
    int rmax = NNODES - base; if (rmax > 64) rmax = 64;
    if (rmax > 0){
      int b = 0;
      while (bstart[b+1] <= base) ++b;
      int bs_next = bstart[b+1];
      float sum = 0.f;
      for (int r = 0; r < rmax; ++r){
        const int grow = base + r;
        while (grow >= bs_next){
          atomicAdd(&pool[b*FDIM + col0 + c], sum);
          sum = 0.f; ++b; bs_next = bstart[b+1];
        }
        sum += (float)sc[(h*64 + r)*128 + c];
      }
      atomicAdd(&pool[b*FDIM + col0 + c], sum);
    }
  }
}

// ---- gather br0 only: grid 5120, blk 256 (2 nodes/block) ----
__global__ __launch_bounds__(256) void k_gath0(const unsigned char* __restrict__ xs8,
                                               const int* __restrict__ rowstart,
                                               const int* __restrict__ csr,
                                               const float* __restrict__ dinv,
                                               unsigned char* __restrict__ xa8){
  const int t = threadIdx.x;
  const int n = blockIdx.x*2 + (t >> 7);
  gather_body(n, 0, t & 127, xs8, rowstart, csr, dinv, xa8);
}

// ---- gemm(br0) || gather(br1): grid 640 + 5120, blk 256 ----
__global__ __launch_bounds__(256) void k_gg(const unsigned char* __restrict__ xa8,
                                            const unsigned char* __restrict__ Wt8,
                                            const float* __restrict__ bg0,
                                            const float* __restrict__ bg1,
                                            const int* __restrict__ bstart,
                                            float* __restrict__ pool,
                                            const unsigned char* __restrict__ xs8,
                                            const int* __restrict__ rowstart,
                                            const int* __restrict__ csr,
                                            const float* __restrict__ dinv){
  __shared__ __align__(16) char smem[32768];
  const int bx = blockIdx.x, t = threadIdx.x;
  if (bx < 640){
    gemm_pool_tile(bx, 0, smem, xa8, Wt8, bg0, bg1, bstart, pool);
  } else {
    const int n = (bx - 640)*2 + (t >> 7);
    gather_body(n, 1, t & 127, xs8, rowstart, csr, dinv, (unsigned char*)xa8);
  }
}

// ---- gemm(br1): grid 640, blk 256 ----
__global__ __launch_bounds__(256) void k_gemm1(const unsigned char* __restrict__ xa8,
                                               const unsigned char* __restrict__ Wt8,
                                               const float* __restrict__ bg0,
                                               const float* __restrict__ bg1,
                                               const int* __restrict__ bstart,
                                               float* __restrict__ pool){
  __shared__ __align__(16) char smem[32768];
  gemm_pool_tile(blockIdx.x, 1, smem, xa8, Wt8, bg0, bg1, bstart, pool);
}

// ---- pf GEMV on pool SUMS; grid (32,2), blk 512 ----
__global__ __launch_bounds__(512) void k_pf(const float* __restrict__ pool_,
                                            const float* __restrict__ W0,
                                            const float* __restrict__ W1,
                                            const float* __restrict__ bias0,
                                            const float* __restrict__ bias1,
                                            const int* __restrict__ bstart_,
                                            float* __restrict__ x12){
  __shared__ float red[512];
  const int br = blockIdx.y, b = blockIdx.x, t = threadIdx.x;
  const int d = t & 127, kq = t >> 7;
  const float* W = (br ? W1 : W0) + (size_t)kq*256*DDIM + d;
  const float* pp = pool_ + (size_t)(br*BGR + b)*FDIM + kq*256;
  float acc = 0.f;
  #pragma unroll 4
  for (int kk = 0; kk < 256; kk += 4){
    const float4 pv = *(const float4*)(pp + kk);
    acc += pv.x * W[(kk  )*DDIM] + pv.y * W[(kk+1)*DDIM]
         + pv.z * W[(kk+2)*DDIM] + pv.w * W[(kk+3)*DDIM];
  }
  red[t] = acc;
  __syncthreads();
  if (t < 128){
    const int* bstart = bstart_ + br*(BGR+1);
    const int cntn = bstart[b+1] - bstart[b];
    const float inv = 1.0f / fmaxf((float)cntn, 1.0f);
    float a = (red[t] + red[t+128] + red[t+256] + red[t+384]) * inv + (br ? bias1 : bias0)[t];
    x12[((size_t)br*BGR + b)*DDIM + t] = lrelu(a);
  }
}

// ---- head: fc1 -> fc2 -> final sigmoid; grid 32, blk 256 ----
__global__ __launch_bounds__(256) void k_head(const float* __restrict__ x12,
                                              const float* __restrict__ Wfc1, const float* __restrict__ bfc1,
                                              const float* __restrict__ Wfc2, const float* __restrict__ bfc2,
                                              const float* __restrict__ m12,
                                              const float* __restrict__ Wout, const float* __restrict__ bout,
                                              float* __restrict__ out){
  __shared__ float xf[256];
  __shared__ float xc[64];
  __shared__ float red[192];
  const int b = blockIdx.x, t = threadIdx.x;
  const float* xin1 = x12 + (size_t)b*DDIM;
  const float* xin2 = x12 + (size_t)(BGR + b)*DDIM;
  float acc = bfc1[t];
  for (int k = 0; k < 128; ++k) acc += xin1[k] * Wfc1[k*256 + t];
  for (int k = 0; k < 128; ++k) acc += xin2[k] * Wfc1[(128+k)*256 + t];
  xf[t] = lrelu(acc);
  __syncthreads();
  if (t < 64){
    float a = bfc2[t];
    for (int k = 0; k < 256; ++k) a += xf[k] * Wfc2[k*64 + t];
    xc[t] = lrelu(a);
  }
  __syncthreads();
  if (t < 192){
    float v;
    if (t < 64)       v = xc[t] * Wout[t];
    else if (t < 128) v = m12[(size_t)b*64 + (t-64)] * Wout[t];
    else              v = m12[(size_t)(BGR + b)*64 + (t-128)] * Wout[t];
    red[t] = v;
  }
  __syncthreads();
  if (t == 0){
    float a = bout[0];
    for (int i = 0; i < 192; ++i) a += red[i];
    out[b] = 1.0f / (1.0f + expf(-a));
  }
}

extern "C" void kernel_launch(void* const* d_in, const int* in_sizes, int n_in,
                              void* d_out, int out_size, void* d_ws, size_t ws_size,
                              hipStream_t stream){
  const float* pro1_x = (const float*)d_in[0];
  const int*   ei1    = (const int*)d_in[1];
  const int*   batch1 = (const int*)d_in[2];
  const float* pro2_x = (const float*)d_in[3];
  const int*   ei2    = (const int*)d_in[4];
  const int*   batch2 = (const int*)d_in[5];
  const float* mas1_s = (const float*)d_in[6];
  const float* mas1_f = (const float*)d_in[7];
  const float* mas2_s = (const float*)d_in[8];
  const float* mas2_f = (const float*)d_in[9];
  const float* W_g1 = (const float*)d_in[10]; const float* b_g1 = (const float*)d_in[11];
  const float* W_g2 = (const float*)d_in[12]; const float* b_g2 = (const float*)d_in[13];
  const float* W_pf1= (const float*)d_in[14]; const float* b_pf1= (const float*)d_in[15];
  const float* W_pf2= (const float*)d_in[16]; const float* b_pf2= (const float*)d_in[17];
  const float* W_fc1= (const float*)d_in[18]; const float* b_fc1= (const float*)d_in[19];
  const float* W_fc2= (const float*)d_in[20]; const float* b_fc2= (const float*)d_in[21];
  const float* cs1w = (const float*)d_in[22]; const float* cs1b = (const float*)d_in[23];
  const float* cf1w = (const float*)d_in[24]; const float* cf1b = (const float*)d_in[25];
  const float* cs2w = (const float*)d_in[26]; const float* cs2b = (const float*)d_in[27];
  const float* cf2w = (const float*)d_in[28]; const float* cf2b = (const float*)d_in[29];
  const float* W_m1 = (const float*)d_in[30]; const float* b_m1 = (const float*)d_in[31];
  const float* W_m2 = (const float*)d_in[32]; const float* b_m2 = (const float*)d_in[33];
  const float* W_out= (const float*)d_in[34]; const float* b_out= (const float*)d_in[35];
  float* out = (float*)d_out;
  (void)in_sizes; (void)n_in; (void)out_size; (void)ws_size;

  char* p = (char*)d_ws;
  auto alloc = [&](size_t bytes)->char*{ char* r = p; p += (bytes + 255) & ~(size_t)255; return r; };
  int*   cntcur = (int*)alloc((size_t)4*NNODES*4);     // cnt, cursor (zeroed)
  float* pool   = (float*)alloc((size_t)2*BGR*FDIM*4); // pool sums (zeroed, adjacent)
  int*   cnt    = cntcur;
  int*   cursor = cntcur + 2*NNODES;
  unsigned char* xs8 = (unsigned char*)alloc((size_t)2*NNODES*FDIM);   // fp8 xs (linear)
  unsigned char* xa8 = (unsigned char*)alloc((size_t)2*NPAD2*FDIM);    // fp8 xa (unit-permuted)
  unsigned char* Wt8 = (unsigned char*)alloc((size_t)2*FDIM*FDIM);     // fp8 W^T (unit-permuted)
  float* dinv = (float*)alloc((size_t)2*NNODES*4);
  int*   rowstart = (int*)alloc((size_t)2*(NNODES+1)*4);
  int*   csr  = (int*)alloc((size_t)2*NEDGES*4);
  int*   bstart = (int*)alloc((size_t)2*(BGR+1)*4);
  float* x12  = (float*)alloc((size_t)2*BGR*DDIM*4);
  float* m12  = (float*)alloc((size_t)2*BGR*64*4);

  // zero cnt+cursor+pool in one DMA (adjacent in the arena)
  hipMemsetAsync(cntcur, 0, (size_t)4*NNODES*4 + (size_t)2*BGR*FDIM*4, stream);
  k_deg<<<NE_BLK, 256, 0, stream>>>(ei1, ei2, cnt);
  k_scan<<<2, 1024, 0, stream>>>(cnt, rowstart, dinv, batch1, batch2, bstart);
  k_misc<<<NE_BLK + 2*NNODES + 2048 + 64, 256, 0, stream>>>(
      ei1, ei2, rowstart, cursor, csr,
      pro1_x, pro2_x, dinv, xs8,
      W_g1, W_g2, Wt8,
      mas1_s, mas1_f, mas2_s, mas2_f,
      cs1w, cs1b, cf1w, cf1b,
      cs2w, cs2b, cf2w, cf2b,
      W_m1, b_m1, W_m2, b_m2, m12);
  k_gath0<<<NPAD2/2, 256, 0, stream>>>(xs8, rowstart, csr, dinv, xa8);
  k_gg<<<640 + NPAD2/2, 256, 0, stream>>>(xa8, Wt8, b_g1, b_g2, bstart, pool,
                                          xs8, rowstart, csr, dinv);
  k_gemm1<<<640, 256, 0, stream>>>(xa8, Wt8, b_g1, b_g2, bstart, pool);
  k_pf<<<dim3(BGR, 2), 512, 0, stream>>>(pool, W_pf1, W_pf2, b_pf1, b_pf2, bstart, x12);
  k_head<<<BGR, 256, 0, stream>>>(x12, W_fc1, b_fc1, W_fc2, b_fc2, m12, W_out, b_out, out);
}

// Round 20
// 156.235 us; speedup vs baseline: 1.1000x; 1.1000x over previous
//
#include <hip/hip_runtime.h>
#include <hip/hip_bf16.h>
#include <math.h>

#define NNODES 10000
#define NEDGES 80000
#define FDIM   1024
#define BGR    32
#define LLEN   800
#define CCH    16
#define DDIM   128
#define NPAD2  10240   // 80 * 128
#define NE_BLK 625     // 2*NEDGES/256

typedef __attribute__((ext_vector_type(4))) _Float16 f16x4;
typedef __attribute__((ext_vector_type(8))) _Float16 f16x8;
typedef __attribute__((ext_vector_type(4))) float f32x4;
typedef __attribute__((ext_vector_type(2))) float f32x2;
typedef __attribute__((ext_vector_type(2))) long long2v;

__device__ __forceinline__ float lrelu(float v){ return v > 0.0f ? v : 0.01f*v; }

// ---- edge in-degree counts only; grid 625, blk 256 ----
__global__ __launch_bounds__(256) void k_deg(const int* __restrict__ ei0, const int* __restrict__ ei1,
                                             int* __restrict__ cnt){
  int i = blockIdx.x*256 + threadIdx.x;
  int br = i >= NEDGES;
  int e  = br ? i - NEDGES : i;
  const int* ei = br ? ei1 : ei0;
  atomicAdd(&cnt[br*NNODES + ei[NEDGES + e]], 1);
}

// ---- per-branch exclusive scan + dinv + bstart; grid=2 blocks of 1024 ----
__global__ __launch_bounds__(1024) void k_scan(const int* __restrict__ cnt, int* __restrict__ rowstart,
                                               float* __restrict__ dinv,
                                               const int* __restrict__ batch0,
                                               const int* __restrict__ batch1,
                                               int* __restrict__ bstart_){
  __shared__ int part[1024];
  const int br = blockIdx.x;
  const int* c = cnt + br*NNODES;
  int* rs = rowstart + br*(NNODES+1);
  float* dv = dinv + br*NNODES;
  const int* batch = br ? batch1 : batch0;
  int* bstart = bstart_ + br*(BGR+1);
  const int t = threadIdx.x;
  const int base = t*10;
  int local[10];
  int s = 0;
  #pragma unroll
  for (int i = 0; i < 10; ++i){
    int v = (base+i < NNODES) ? c[base+i] : 0;
    local[i] = s; s += v;
    if (base+i < NNODES) dv[base+i] = rsqrtf((float)v + 1.0f);
  }
  part[t] = s;
  __syncthreads();
  for (int off = 1; off < 1024; off <<= 1){
    int v = (t >= off) ? part[t-off] : 0;
    __syncthreads();
    part[t] += v;
    __syncthreads();
  }
  const int prev = (t == 0) ? 0 : part[t-1];
  #pragma unroll
  for (int i = 0; i < 10; ++i)
    if (base+i < NNODES) rs[base+i] = prev + local[i];
  if (t == 0) rs[NNODES] = NEDGES;
  for (int i = base; i < base+10 && i < NNODES; ++i){
    int b = batch[i];
    if (i == 0){ for (int bb = 0; bb <= b; ++bb) bstart[bb] = 0; }
    else {
      int pb = batch[i-1];
      if (b != pb) for (int bb = pb+1; bb <= b; ++bb) bstart[bb] = i;
    }
    if (i == NNODES-1){ for (int bb = b+1; bb <= BGR; ++bb) bstart[bb] = NNODES; }
  }
}

// ---- wide misc: CSR fill || cvtX(fp8) || cvtW(fp8, unit-permuted) || masif ----
__global__ __launch_bounds__(256) void k_misc(const int* __restrict__ ei0, const int* __restrict__ ei1,
                                              const int* __restrict__ rowstart,
                                              int* __restrict__ cursor, int* __restrict__ csr,
                                              const float* __restrict__ x0, const float* __restrict__ x1,
                                              const float* __restrict__ dinv,
                                              unsigned char* __restrict__ xs8,
                                              const float* __restrict__ W0, const float* __restrict__ W1,
                                              unsigned char* __restrict__ Wt8,
                                              const float* __restrict__ ms1, const float* __restrict__ mf1,
                                              const float* __restrict__ ms2, const float* __restrict__ mf2,
                                              const float* __restrict__ sw1, const float* __restrict__ sb1,
                                              const float* __restrict__ fw1, const float* __restrict__ fb1,
                                              const float* __restrict__ sw2, const float* __restrict__ sb2,
                                              const float* __restrict__ fw2, const float* __restrict__ fb2,
                                              const float* __restrict__ Wm1, const float* __restrict__ bm1,
                                              const float* __restrict__ Wm2, const float* __restrict__ bm2,
                                              float* __restrict__ m12){
  __shared__ float tl[32][33];
  __shared__ float sf[LLEN];
  __shared__ float w80[80];
  const int bx = blockIdx.x, t = threadIdx.x;
  if (bx < NE_BLK){
    // CSR fill
    const int i = bx*256 + t;
    const int br = i >= NEDGES;
    const int e  = br ? i - NEDGES : i;
    const int* ei = br ? ei1 : ei0;
    const int r = ei[e], c = ei[NEDGES + e];
    const int pos = atomicAdd(&cursor[br*NNODES + c], 1);
    csr[br*NEDGES + rowstart[br*(NNODES+1) + c] + pos] = r;
  } else if (bx < NE_BLK + 2*NNODES){
    // cvtX: xs8[row] = fp8(dinv[row] * x[row]); LINEAR layout (gather input)
    const int idx = bx - NE_BLK;              // 0..19999
    const int br = idx >= NNODES;
    const int row = br ? idx - NNODES : idx;
    const float* x = (br ? x1 : x0) + (size_t)row*FDIM;
    unsigned char* o = xs8 + ((size_t)br*NNODES + row)*FDIM;
    const int f = t*4;
    const float d = dinv[br*NNODES + row];
    const float4 v = *(const float4*)(x + f);
    int p = __builtin_amdgcn_cvt_pk_fp8_f32(v.x*d, v.y*d, 0, false);
    p = __builtin_amdgcn_cvt_pk_fp8_f32(v.z*d, v.w*d, p, true);
    *(int*)(o + f) = p;
  } else if (bx < NE_BLK + 2*NNODES + 2048){
    // cvtW transpose + fp8 cast, UNIT-PERMUTED within each 64B k-group:
    // 8B unit u -> position 2*(u&3)+(u>>2); phys slot p holds units {p, p+4}.
    const int idx = bx - NE_BLK - 2*NNODES;
    const int br = idx >> 10, tile = idx & 1023;
    const float* W = br ? W1 : W0;
    unsigned char* Wo = Wt8 + (size_t)br*FDIM*FDIM;
    const int k0 = (tile >> 5)*32, n0 = (tile & 31)*32;
    const int r = t >> 3, c4 = (t & 7)*4;
    const float4 v = *(const float4*)(W + (size_t)(k0+r)*FDIM + n0 + c4);
    tl[r][c4] = v.x; tl[r][c4+1] = v.y; tl[r][c4+2] = v.z; tl[r][c4+3] = v.w;
    __syncthreads();
    int p = __builtin_amdgcn_cvt_pk_fp8_f32(tl[c4  ][r], tl[c4+1][r], 0, false);
    p = __builtin_amdgcn_cvt_pk_fp8_f32(tl[c4+2][r], tl[c4+3][r], p, true);
    const int L = k0 + c4;                           // logical k-byte
    const int g = L >> 6, u = (L >> 3) & 7, h = (L >> 2) & 1;
    const int Lp = g*64 + (2*(u&3) + (u>>2))*8 + h*4;
    *(int*)(Wo + (size_t)(n0+r)*FDIM + Lp) = p;
  } else {
    // masif
    const int idx = bx - NE_BLK - 2*NNODES - 2048;   // 0..63
    const int br = idx >> 5, b = idx & 31;
    const float* ms = br ? ms2 : ms1;
    const float* mf = br ? mf2 : mf1;
    const float swv = (br ? sw2 : sw1)[0], sbv = (br ? sb2 : sb1)[0];
    const float fwv = (br ? fw2 : fw1)[0], fbv = (br ? fb2 : fb1)[0];
    const float* Wm = br ? Wm2 : Wm1;
    const float* bm = br ? bm2 : bm1;
    for (int l = t; l < LLEN; l += 256){
      float sm = 0.f, fm = 0.f;
      for (int c = 0; c < CCH; ++c){
        sm += ms[((size_t)b*CCH + c)*LLEN + l];
        fm += mf[((size_t)b*CCH + c)*LLEN + l];
      }
      sm = fmaxf(sm*(1.0f/16.0f)*swv + sbv, 0.f);
      fm = fmaxf(fm*(1.0f/16.0f)*fwv + fbv, 0.f);
      sf[l] = sm + fm;
    }
    __syncthreads();
    if (t < 80){
      float a = 0.f;
      for (int j = 0; j < 10; ++j) a += sf[t*10 + j];
      w80[t] = a * 0.05f;
    }
    __syncthreads();
    if (t < 64){
      float acc = bm[t];
      for (int k = 0; k < 80; ++k) acc += w80[k] * Wm[k*64 + t];
      m12[((size_t)br*BGR + b)*64 + t] = acc;
    }
  }
}

// ---- gather (fp8 in linear, fp8 out UNIT-PERMUTED): grid (NPAD2/2, 2), blk 256 ----
__global__ __launch_bounds__(256) void k_gath(const unsigned char* __restrict__ xs8_,
                                              const int* __restrict__ rowstart_,
                                              const int* __restrict__ csr_,
                                              const float* __restrict__ dinv_,
                                              unsigned char* __restrict__ xa8_){
  const int t = threadIdx.x;
  const int br = blockIdx.y;
  const int n = blockIdx.x*2 + (t >> 7);
  const int lt = t & 127;

  const unsigned char* xs8 = xs8_ + (size_t)br*NNODES*FDIM;
  const int* rowstart = rowstart_ + br*(NNODES+1);
  const int* csr = csr_ + br*NEDGES;
  const float* dinv = dinv_ + br*NNODES;
  unsigned char* xa8 = xa8_ + (size_t)br*NPAD2*FDIM;

  const int f = lt*8;                               // logical k-range read
  const int g = lt >> 3, u = lt & 7;                // permuted write position
  const int fp = g*64 + (2*(u&3) + (u>>2))*8;
  unsigned char* op = xa8 + (size_t)n*FDIM + fp;
  if (n >= NNODES){
    *(long*)op = 0L;
    return;
  }
  const int s0 = rowstart[n], s1 = rowstart[n+1];
  float a0=0,a1=0,a2=0,a3=0,a4=0,a5=0,a6=0,a7=0;
  auto addrow = [&](uint2 q){
    f32x2 w0 = __builtin_amdgcn_cvt_pk_f32_fp8((int)q.x, false);
    f32x2 w1 = __builtin_amdgcn_cvt_pk_f32_fp8((int)q.x, true);
    f32x2 w2 = __builtin_amdgcn_cvt_pk_f32_fp8((int)q.y, false);
    f32x2 w3 = __builtin_amdgcn_cvt_pk_f32_fp8((int)q.y, true);
    a0 += w0[0]; a1 += w0[1]; a2 += w1[0]; a3 += w1[1];
    a4 += w2[0]; a5 += w2[1]; a6 += w3[0]; a7 += w3[1];
  };
  addrow(*(const uint2*)(xs8 + (size_t)n*FDIM + f));   // self-loop
  int i = s0;
  for (; i + 4 <= s1; i += 4){
    const int r0 = csr[i], r1 = csr[i+1], r2 = csr[i+2], r3 = csr[i+3];
    const uint2 q0 = *(const uint2*)(xs8 + (size_t)r0*FDIM + f);
    const uint2 q1 = *(const uint2*)(xs8 + (size_t)r1*FDIM + f);
    const uint2 q2 = *(const uint2*)(xs8 + (size_t)r2*FDIM + f);
    const uint2 q3 = *(const uint2*)(xs8 + (size_t)r3*FDIM + f);
    addrow(q0); addrow(q1); addrow(q2); addrow(q3);
  }
  for (; i < s1; ++i){
    addrow(*(const uint2*)(xs8 + (size_t)csr[i]*FDIM + f));
  }
  const float d = dinv[n];
  uint2 o;
  int p0 = __builtin_amdgcn_cvt_pk_fp8_f32(a0*d, a1*d, 0, false);
  p0 = __builtin_amdgcn_cvt_pk_fp8_f32(a2*d, a3*d, p0, true);
  int p1 = __builtin_amdgcn_cvt_pk_fp8_f32(a4*d, a5*d, 0, false);
  p1 = __builtin_amdgcn_cvt_pk_fp8_f32(a6*d, a7*d, p1, true);
  o.x = (unsigned)p0; o.y = (unsigned)p1;
  *(uint2*)op = o;
}

// ---- fp8 GEMM + fused pooling. grid 1280 (= 8*160 XCD-local), blk 256 ----
// 128x128 tile, BK=64, unit-permuted operands: phys 16B slot p of each 64B
// k-group holds lane-p's (j=0, j=1) MFMA fragments -> ONE ds_read_b128 per
// (i, matrix); 16-lane bank spans all-distinct (2-way, free). Swizzle
// slot ^= (row>>1)&3 on stage source + read addr (both-sides).
__global__ __launch_bounds__(256) void k_gemm(const unsigned char* __restrict__ A_,
                                              const unsigned char* __restrict__ Bt_,
                                              const float* __restrict__ bg0,
                                              const float* __restrict__ bg1,
                                              const int* __restrict__ bstart_,
                                              float* __restrict__ pool_){
  __shared__ __align__(16) char smem[32768];  // As[2]:0..16K, Bs[2]:16K..32K; epilogue scratch all 32K
  const int id  = blockIdx.x;                 // 0..1279
  const int w   = (id & 7)*160 + (id >> 3);   // XCD-local bijection
  const int col = w & 7;
  const int ru  = w >> 3;                     // 0..159
  const int row = ru % 80;
  const int br  = ru / 80;

  const unsigned char* A  = A_  + (size_t)br*NPAD2*FDIM;
  const unsigned char* Bt = Bt_ + (size_t)br*FDIM*FDIM;
  const float* bg = br ? bg1 : bg0;
  const int* bstart = bstart_ + br*(BGR+1);
  float* pool = pool_ + br*BGR*FDIM;

  const int row0 = row*128, col0 = col*128;
  const int tid  = threadIdx.x;
  const int lane = tid & 63, wave = tid >> 6;
  const int wm = wave >> 1, wn = wave & 1;
  const int lr = lane >> 2;       // 0..15 row within 16-row staging group
  const int ls = lane & 3;        // linear 16B slot within 64B row

  f32x4 acc[4][4] = {};

  auto stage = [&](int buf, int k0){
    char* Asb = smem + buf*8192;
    char* Bsb = smem + 16384 + buf*8192;
    #pragma unroll
    for (int j = 0; j < 2; ++j){
      const int r0 = wave*32 + j*16;
      const int ra = r0 + lr;
      const int sa = ls ^ ((ra >> 1) & 3);    // pre-swizzled 16B slot
      __builtin_amdgcn_global_load_lds(
        (const __attribute__((address_space(1))) void*)(A + (size_t)(row0+ra)*FDIM + k0 + sa*16),
        (__attribute__((address_space(3))) void*)(Asb + r0*64), 16, 0, 0);
      __builtin_amdgcn_global_load_lds(
        (const __attribute__((address_space(1))) void*)(Bt + (size_t)(col0+ra)*FDIM + k0 + sa*16),
        (__attribute__((address_space(3))) void*)(Bsb + r0*64), 16, 0, 0);
    }
  };

  auto compute = [&](int buf){
    const char* Asb = smem + buf*8192;
    const char* Bsb = smem + 16384 + buf*8192;
    long2v af[4], bf[4];
    const int s = lane >> 4;        // 0..3 = phys slot this lane consumes
    #pragma unroll
    for (int i = 0; i < 4; ++i){
      const int rA = wm*64 + i*16 + (lane & 15);
      af[i] = *(const long2v*)(Asb + rA*64 + ((s ^ ((rA>>1)&3))<<4));
      const int rB = wn*64 + i*16 + (lane & 15);
      bf[i] = *(const long2v*)(Bsb + rB*64 + ((s ^ ((rB>>1)&3))<<4));
    }
    #pragma unroll
    for (int mi = 0; mi < 4; ++mi)
      #pragma unroll
      for (int ni = 0; ni < 4; ++ni){
        acc[mi][ni] = __builtin_amdgcn_mfma_f32_16x16x32_fp8_fp8(af[mi][0], bf[ni][0], acc[mi][ni], 0, 0, 0);
        acc[mi][ni] = __builtin_amdgcn_mfma_f32_16x16x32_fp8_fp8(af[mi][1], bf[ni][1], acc[mi][ni], 0, 0, 0);
      }
  };

  stage(0, 0);                                 // 4 loads in flight
  #pragma unroll 2
  for (int ks = 0; ks < 16; ++ks){
    if (ks < 15){
      stage((ks+1)&1, (ks+1)*64);              // +4 -> 8 in flight
      asm volatile("s_waitcnt vmcnt(4)" ::: "memory");   // current tile landed
    } else {
      asm volatile("s_waitcnt vmcnt(0)" ::: "memory");
    }
    __builtin_amdgcn_s_barrier();              // next tile's loads stay in flight
    compute(ks&1);
    __builtin_amdgcn_s_barrier();              // reads done before overwrite
  }
  __syncthreads();   // drain before scratch overwrite

  // write output tile (f16, post bias+lrelu; 0 for pad rows) into 32KB scratch
  _Float16* sc = (_Float16*)smem;
  float bcol[4];
  #pragma unroll
  for (int ni = 0; ni < 4; ++ni) bcol[ni] = bg[col0 + wn*64 + ni*16 + (lane & 15)];
  #pragma unroll
  for (int mi = 0; mi < 4; ++mi){
    #pragma unroll
    for (int j = 0; j < 4; ++j){
      const int lrow = wm*64 + mi*16 + (lane>>4)*4 + j;
      const int valid = (row0 + lrow) < NNODES;
      #pragma unroll
      for (int ni = 0; ni < 4; ++ni){
        const int lcol = wn*64 + ni*16 + (lane & 15);
        sc[lrow*128 + lcol] = valid ? (_Float16)lrelu(acc[mi][ni][j] + bcol[ni]) : (_Float16)0.f;
      }
    }
  }
  __syncthreads();

  // per-column batch-segment sums: thread t owns col c = t&127, half h = t>>7
  {
    const int c = tid & 127, h = tid >> 7;
    const int base = row0 + h*64;
    int rmax = NNODES - base; if (rmax > 64) rmax = 64;
    if (rmax > 0){
      int b = 0;
      while (bstart[b+1] <= base) ++b;
      int bs_next = bstart[b+1];
      float sum = 0.f;
      for (int r = 0; r < rmax; ++r){
        const int grow = base + r;
        while (grow >= bs_next){
          atomicAdd(&pool[b*FDIM + col0 + c], sum);
          sum = 0.f; ++b; bs_next = bstart[b+1];
        }
        sum += (float)sc[(h*64 + r)*128 + c];
      }
      atomicAdd(&pool[b*FDIM + col0 + c], sum);
    }
  }
}

// ---- pf GEMV on pool SUMS; grid (32,2), blk 512 ----
__global__ __launch_bounds__(512) void k_pf(const float* __restrict__ pool_,
                                            const float* __restrict__ W0,
                                            const float* __restrict__ W1,
                                            const float* __restrict__ bias0,
                                            const float* __restrict__ bias1,
                                            const int* __restrict__ bstart_,
                                            float* __restrict__ x12){
  __shared__ float red[512];
  const int br = blockIdx.y, b = blockIdx.x, t = threadIdx.x;
  const int d = t & 127, kq = t >> 7;
  const float* W = (br ? W1 : W0) + (size_t)kq*256*DDIM + d;
  const float* pp = pool_ + (size_t)(br*BGR + b)*FDIM + kq*256;
  float acc = 0.f;
  #pragma unroll 4
  for (int kk = 0; kk < 256; kk += 4){
    const float4 pv = *(const float4*)(pp + kk);
    acc += pv.x * W[(kk  )*DDIM] + pv.y * W[(kk+1)*DDIM]
         + pv.z * W[(kk+2)*DDIM] + pv.w * W[(kk+3)*DDIM];
  }
  red[t] = acc;
  __syncthreads();
  if (t < 128){
    const int* bstart = bstart_ + br*(BGR+1);
    const int cntn = bstart[b+1] - bstart[b];
    const float inv = 1.0f / fmaxf((float)cntn, 1.0f);
    float a = (red[t] + red[t+128] + red[t+256] + red[t+384]) * inv + (br ? bias1 : bias0)[t];
    x12[((size_t)br*BGR + b)*DDIM + t] = lrelu(a);
  }
}

// ---- head: fc1 -> fc2 -> final sigmoid; grid 32, blk 256 ----
__global__ __launch_bounds__(256) void k_head(const float* __restrict__ x12,
                                              const float* __restrict__ Wfc1, const float* __restrict__ bfc1,
                                              const float* __restrict__ Wfc2, const float* __restrict__ bfc2,
                                              const float* __restrict__ m12,
                                              const float* __restrict__ Wout, const float* __restrict__ bout,
                                              float* __restrict__ out){
  __shared__ float xf[256];
  __shared__ float xc[64];
  __shared__ float red[192];
  const int b = blockIdx.x, t = threadIdx.x;
  const float* xin1 = x12 + (size_t)b*DDIM;
  const float* xin2 = x12 + (size_t)(BGR + b)*DDIM;
  float acc = bfc1[t];
  for (int k = 0; k < 128; ++k) acc += xin1[k] * Wfc1[k*256 + t];
  for (int k = 0; k < 128; ++k) acc += xin2[k] * Wfc1[(128+k)*256 + t];
  xf[t] = lrelu(acc);
  __syncthreads();
  if (t < 64){
    float a = bfc2[t];
    for (int k = 0; k < 256; ++k) a += xf[k] * Wfc2[k*64 + t];
    xc[t] = lrelu(a);
  }
  __syncthreads();
  if (t < 192){
    float v;
    if (t < 64)       v = xc[t] * Wout[t];
    else if (t < 128) v = m12[(size_t)b*64 + (t-64)] * Wout[t];
    else              v = m12[(size_t)(BGR + b)*64 + (t-128)] * Wout[t];
    red[t] = v;
  }
  __syncthreads();
  if (t == 0){
    float a = bout[0];
    for (int i = 0; i < 192; ++i) a += red[i];
    out[b] = 1.0f / (1.0f + expf(-a));
  }
}

extern "C" void kernel_launch(void* const* d_in, const int* in_sizes, int n_in,
                              void* d_out, int out_size, void* d_ws, size_t ws_size,
                              hipStream_t stream){
  const float* pro1_x = (const float*)d_in[0];
  const int*   ei1    = (const int*)d_in[1];
  const int*   batch1 = (const int*)d_in[2];
  const float* pro2_x = (const float*)d_in[3];
  const int*   ei2    = (const int*)d_in[4];
  const int*   batch2 = (const int*)d_in[5];
  const float* mas1_s = (const float*)d_in[6];
  const float* mas1_f = (const float*)d_in[7];
  const float* mas2_s = (const float*)d_in[8];
  const float* mas2_f = (const float*)d_in[9];
  const float* W_g1 = (const float*)d_in[10]; const float* b_g1 = (const float*)d_in[11];
  const float* W_g2 = (const float*)d_in[12]; const float* b_g2 = (const float*)d_in[13];
  const float* W_pf1= (const float*)d_in[14]; const float* b_pf1= (const float*)d_in[15];
  const float* W_pf2= (const float*)d_in[16]; const float* b_pf2= (const float*)d_in[17];
  const float* W_fc1= (const float*)d_in[18]; const float* b_fc1= (const float*)d_in[19];
  const float* W_fc2= (const float*)d_in[20]; const float* b_fc2= (const float*)d_in[21];
  const float* cs1w = (const float*)d_in[22]; const float* cs1b = (const float*)d_in[23];
  const float* cf1w = (const float*)d_in[24]; const float* cf1b = (const float*)d_in[25];
  const float* cs2w = (const float*)d_in[26]; const float* cs2b = (const float*)d_in[27];
  const float* cf2w = (const float*)d_in[28]; const float* cf2b = (const float*)d_in[29];
  const float* W_m1 = (const float*)d_in[30]; const float* b_m1 = (const float*)d_in[31];
  const float* W_m2 = (const float*)d_in[32]; const float* b_m2 = (const float*)d_in[33];
  const float* W_out= (const float*)d_in[34]; const float* b_out= (const float*)d_in[35];
  float* out = (float*)d_out;
  (void)in_sizes; (void)n_in; (void)out_size; (void)ws_size;

  char* p = (char*)d_ws;
  auto alloc = [&](size_t bytes)->char*{ char* r = p; p += (bytes + 255) & ~(size_t)255; return r; };
  int*   cntcur = (int*)alloc((size_t)4*NNODES*4);     // cnt, cursor (zeroed)
  float* pool   = (float*)alloc((size_t)2*BGR*FDIM*4); // pool sums (zeroed, adjacent)
  int*   cnt    = cntcur;
  int*   cursor = cntcur + 2*NNODES;
  unsigned char* xs8 = (unsigned char*)alloc((size_t)2*NNODES*FDIM);   // fp8 xs (linear)
  unsigned char* xa8 = (unsigned char*)alloc((size_t)2*NPAD2*FDIM);    // fp8 xa (unit-permuted)
  unsigned char* Wt8 = (unsigned char*)alloc((size_t)2*FDIM*FDIM);     // fp8 W^T (unit-permuted)
  float* dinv = (float*)alloc((size_t)2*NNODES*4);
  int*   rowstart = (int*)alloc((size_t)2*(NNODES+1)*4);
  int*   csr  = (int*)alloc((size_t)2*NEDGES*4);
  int*   bstart = (int*)alloc((size_t)2*(BGR+1)*4);
  float* x12  = (float*)alloc((size_t)2*BGR*DDIM*4);
  float* m12  = (float*)alloc((size_t)2*BGR*64*4);

  // zero cnt+cursor+pool in one DMA (adjacent in the arena)
  hipMemsetAsync(cntcur, 0, (size_t)4*NNODES*4 + (size_t)2*BGR*FDIM*4, stream);
  k_deg<<<NE_BLK, 256, 0, stream>>>(ei1, ei2, cnt);
  k_scan<<<2, 1024, 0, stream>>>(cnt, rowstart, dinv, batch1, batch2, bstart);
  k_misc<<<NE_BLK + 2*NNODES + 2048 + 64, 256, 0, stream>>>(
      ei1, ei2, rowstart, cursor, csr,
      pro1_x, pro2_x, dinv, xs8,
      W_g1, W_g2, Wt8,
      mas1_s, mas1_f, mas2_s, mas2_f,
      cs1w, cs1b, cf1w, cf1b,
      cs2w, cs2b, cf2w, cf2b,
      W_m1, b_m1, W_m2, b_m2, m12);
  k_gath<<<dim3(NPAD2/2, 2), 256, 0, stream>>>(xs8, rowstart, csr, dinv, xa8);
  k_gemm<<<1280, 256, 0, stream>>>(xa8, Wt8, b_g1, b_g2, bstart, pool);
  k_pf<<<dim3(BGR, 2), 512, 0, stream>>>(pool, W_pf1, W_pf2, b_pf1, b_pf2, bstart, x12);
  k_head<<<BGR, 256, 0, stream>>>(x12, W_fc1, b_fc1, W_fc2, b_fc2, m12, W_out, b_out, out);
}

// Round 21
// 155.546 us; speedup vs baseline: 1.1049x; 1.0044x over previous
//
#include <hip/hip_runtime.h>
#include <hip/hip_bf16.h>
#include <math.h>

#define NNODES 10000
#define NEDGES 80000
#define FDIM   1024
#define BGR    32
#define LLEN   800
#define CCH    16
#define DDIM   128
#define NPAD2  10240   // 80 * 128
#define NE_BLK 625     // 2*NEDGES/256
#define MAS_BLK 256    // 2 br * 32 b * 4 quarters

typedef __attribute__((ext_vector_type(4))) _Float16 f16x4;
typedef __attribute__((ext_vector_type(8))) _Float16 f16x8;
typedef __attribute__((ext_vector_type(4))) float f32x4;
typedef __attribute__((ext_vector_type(2))) float f32x2;
typedef __attribute__((ext_vector_type(2))) long long2v;

__device__ __forceinline__ float lrelu(float v){ return v > 0.0f ? v : 0.01f*v; }

// ---- edge in-degree counts only; grid 625, blk 256 ----
__global__ __launch_bounds__(256) void k_deg(const int* __restrict__ ei0, const int* __restrict__ ei1,
                                             int* __restrict__ cnt){
  int i = blockIdx.x*256 + threadIdx.x;
  int br = i >= NEDGES;
  int e  = br ? i - NEDGES : i;
  const int* ei = br ? ei1 : ei0;
  atomicAdd(&cnt[br*NNODES + ei[NEDGES + e]], 1);
}

// ---- per-branch exclusive scan + dinv + bstart; grid=2 blocks of 1024 ----
__global__ __launch_bounds__(1024) void k_scan(const int* __restrict__ cnt, int* __restrict__ rowstart,
                                               float* __restrict__ dinv,
                                               const int* __restrict__ batch0,
                                               const int* __restrict__ batch1,
                                               int* __restrict__ bstart_){
  __shared__ int part[1024];
  const int br = blockIdx.x;
  const int* c = cnt + br*NNODES;
  int* rs = rowstart + br*(NNODES+1);
  float* dv = dinv + br*NNODES;
  const int* batch = br ? batch1 : batch0;
  int* bstart = bstart_ + br*(BGR+1);
  const int t = threadIdx.x;
  const int base = t*10;
  int local[10];
  int s = 0;
  #pragma unroll
  for (int i = 0; i < 10; ++i){
    int v = (base+i < NNODES) ? c[base+i] : 0;
    local[i] = s; s += v;
    if (base+i < NNODES) dv[base+i] = rsqrtf((float)v + 1.0f);
  }
  part[t] = s;
  __syncthreads();
  for (int off = 1; off < 1024; off <<= 1){
    int v = (t >= off) ? part[t-off] : 0;
    __syncthreads();
    part[t] += v;
    __syncthreads();
  }
  const int prev = (t == 0) ? 0 : part[t-1];
  #pragma unroll
  for (int i = 0; i < 10; ++i)
    if (base+i < NNODES) rs[base+i] = prev + local[i];
  if (t == 0) rs[NNODES] = NEDGES;
  for (int i = base; i < base+10 && i < NNODES; ++i){
    int b = batch[i];
    if (i == 0){ for (int bb = 0; bb <= b; ++bb) bstart[bb] = 0; }
    else {
      int pb = batch[i-1];
      if (b != pb) for (int bb = pb+1; bb <= b; ++bb) bstart[bb] = i;
    }
    if (i == NNODES-1){ for (int bb = b+1; bb <= BGR; ++bb) bstart[bb] = NNODES; }
  }
}

// ---- wide misc: masif-partial (FIRST) || CSR fill || cvtW(fp8, permuted) || cvtX(fp8) ----
// masif-partial: 256 blocks, each sums 4 channels of ms/mf into spart/fpart (no atomics).
__global__ __launch_bounds__(256) void k_misc(const int* __restrict__ ei0, const int* __restrict__ ei1,
                                              const int* __restrict__ rowstart,
                                              int* __restrict__ cursor, int* __restrict__ csr,
                                              const float* __restrict__ x0, const float* __restrict__ x1,
                                              const float* __restrict__ dinv,
                                              unsigned char* __restrict__ xs8,
                                              const float* __restrict__ W0, const float* __restrict__ W1,
                                              unsigned char* __restrict__ Wt8,
                                              const float* __restrict__ ms1, const float* __restrict__ mf1,
                                              const float* __restrict__ ms2, const float* __restrict__ mf2,
                                              float* __restrict__ spart, float* __restrict__ fpart){
  __shared__ float tl[32][33];
  const int bx = blockIdx.x, t = threadIdx.x;
  if (bx < MAS_BLK){
    // masif channel-quarter partial sums: idx -> (br, b, q)
    const int idx = bx;
    const int br = idx >> 7, rem = idx & 127;
    const int b = rem >> 2, q = rem & 3;
    const float* ms = br ? ms2 : ms1;
    const float* mf = br ? mf2 : mf1;
    float* sp = spart + (((size_t)br*BGR + b)*4 + q)*LLEN;
    float* fp = fpart + (((size_t)br*BGR + b)*4 + q)*LLEN;
    for (int l = t; l < LLEN; l += 256){
      float sm = 0.f, fm = 0.f;
      #pragma unroll
      for (int c = 0; c < 4; ++c){
        sm += ms[((size_t)b*CCH + q*4 + c)*LLEN + l];
        fm += mf[((size_t)b*CCH + q*4 + c)*LLEN + l];
      }
      sp[l] = sm; fp[l] = fm;
    }
  } else if (bx < MAS_BLK + NE_BLK){
    // CSR fill
    const int i = (bx - MAS_BLK)*256 + t;
    const int br = i >= NEDGES;
    const int e  = br ? i - NEDGES : i;
    const int* ei = br ? ei1 : ei0;
    const int r = ei[e], c = ei[NEDGES + e];
    const int pos = atomicAdd(&cursor[br*NNODES + c], 1);
    csr[br*NEDGES + rowstart[br*(NNODES+1) + c] + pos] = r;
  } else if (bx < MAS_BLK + NE_BLK + 2048){
    // cvtW transpose + fp8 cast, UNIT-PERMUTED within each 64B k-group
    const int idx = bx - MAS_BLK - NE_BLK;
    const int br = idx >> 10, tile = idx & 1023;
    const float* W = br ? W1 : W0;
    unsigned char* Wo = Wt8 + (size_t)br*FDIM*FDIM;
    const int k0 = (tile >> 5)*32, n0 = (tile & 31)*32;
    const int r = t >> 3, c4 = (t & 7)*4;
    const float4 v = *(const float4*)(W + (size_t)(k0+r)*FDIM + n0 + c4);
    tl[r][c4] = v.x; tl[r][c4+1] = v.y; tl[r][c4+2] = v.z; tl[r][c4+3] = v.w;
    __syncthreads();
    int p = __builtin_amdgcn_cvt_pk_fp8_f32(tl[c4  ][r], tl[c4+1][r], 0, false);
    p = __builtin_amdgcn_cvt_pk_fp8_f32(tl[c4+2][r], tl[c4+3][r], p, true);
    const int L = k0 + c4;                           // logical k-byte
    const int g = L >> 6, u = (L >> 3) & 7, h = (L >> 2) & 1;
    const int Lp = g*64 + (2*(u&3) + (u>>2))*8 + h*4;
    *(int*)(Wo + (size_t)(n0+r)*FDIM + Lp) = p;
  } else {
    // cvtX: xs8[row] = fp8(dinv[row] * x[row]); LINEAR layout
    const int idx = bx - MAS_BLK - NE_BLK - 2048;   // 0..19999
    const int br = idx >= NNODES;
    const int row = br ? idx - NNODES : idx;
    const float* x = (br ? x1 : x0) + (size_t)row*FDIM;
    unsigned char* o = xs8 + ((size_t)br*NNODES + row)*FDIM;
    const int f = t*4;
    const float d = dinv[br*NNODES + row];
    const float4 v = *(const float4*)(x + f);
    int p = __builtin_amdgcn_cvt_pk_fp8_f32(v.x*d, v.y*d, 0, false);
    p = __builtin_amdgcn_cvt_pk_fp8_f32(v.z*d, v.w*d, p, true);
    *(int*)(o + f) = p;
  }
}

// ---- gather (fp8 in linear, fp8 out UNIT-PERMUTED): grid (NPAD2/2, 2), blk 256 ----
__global__ __launch_bounds__(256) void k_gath(const unsigned char* __restrict__ xs8_,
                                              const int* __restrict__ rowstart_,
                                              const int* __restrict__ csr_,
                                              const float* __restrict__ dinv_,
                                              unsigned char* __restrict__ xa8_){
  const int t = threadIdx.x;
  const int br = blockIdx.y;
  const int n = blockIdx.x*2 + (t >> 7);
  const int lt = t & 127;

  const unsigned char* xs8 = xs8_ + (size_t)br*NNODES*FDIM;
  const int* rowstart = rowstart_ + br*(NNODES+1);
  const int* csr = csr_ + br*NEDGES;
  const float* dinv = dinv_ + br*NNODES;
  unsigned char* xa8 = xa8_ + (size_t)br*NPAD2*FDIM;

  const int f = lt*8;                               // logical k-range read
  const int g = lt >> 3, u = lt & 7;                // permuted write position
  const int fp = g*64 + (2*(u&3) + (u>>2))*8;
  unsigned char* op = xa8 + (size_t)n*FDIM + fp;
  if (n >= NNODES){
    *(long*)op = 0L;
    return;
  }
  const int s0 = rowstart[n], s1 = rowstart[n+1];
  float a0=0,a1=0,a2=0,a3=0,a4=0,a5=0,a6=0,a7=0;
  auto addrow = [&](uint2 q){
    f32x2 w0 = __builtin_amdgcn_cvt_pk_f32_fp8((int)q.x, false);
    f32x2 w1 = __builtin_amdgcn_cvt_pk_f32_fp8((int)q.x, true);
    f32x2 w2 = __builtin_amdgcn_cvt_pk_f32_fp8((int)q.y, false);
    f32x2 w3 = __builtin_amdgcn_cvt_pk_f32_fp8((int)q.y, true);
    a0 += w0[0]; a1 += w0[1]; a2 += w1[0]; a3 += w1[1];
    a4 += w2[0]; a5 += w2[1]; a6 += w3[0]; a7 += w3[1];
  };
  addrow(*(const uint2*)(xs8 + (size_t)n*FDIM + f));   // self-loop
  int i = s0;
  for (; i + 4 <= s1; i += 4){
    const int r0 = csr[i], r1 = csr[i+1], r2 = csr[i+2], r3 = csr[i+3];
    const uint2 q0 = *(const uint2*)(xs8 + (size_t)r0*FDIM + f);
    const uint2 q1 = *(const uint2*)(xs8 + (size_t)r1*FDIM + f);
    const uint2 q2 = *(const uint2*)(xs8 + (size_t)r2*FDIM + f);
    const uint2 q3 = *(const uint2*)(xs8 + (size_t)r3*FDIM + f);
    addrow(q0); addrow(q1); addrow(q2); addrow(q3);
  }
  for (; i < s1; ++i){
    addrow(*(const uint2*)(xs8 + (size_t)csr[i]*FDIM + f));
  }
  const float d = dinv[n];
  uint2 o;
  int p0 = __builtin_amdgcn_cvt_pk_fp8_f32(a0*d, a1*d, 0, false);
  p0 = __builtin_amdgcn_cvt_pk_fp8_f32(a2*d, a3*d, p0, true);
  int p1 = __builtin_amdgcn_cvt_pk_fp8_f32(a4*d, a5*d, 0, false);
  p1 = __builtin_amdgcn_cvt_pk_fp8_f32(a6*d, a7*d, p1, true);
  o.x = (unsigned)p0; o.y = (unsigned)p1;
  *(uint2*)op = o;
}

// ---- fp8 GEMM + fused pooling (R18-proven, unchanged). grid 1280, blk 256 ----
__global__ __launch_bounds__(256) void k_gemm(const unsigned char* __restrict__ A_,
                                              const unsigned char* __restrict__ Bt_,
                                              const float* __restrict__ bg0,
                                              const float* __restrict__ bg1,
                                              const int* __restrict__ bstart_,
                                              float* __restrict__ pool_){
  __shared__ __align__(16) char smem[32768];  // As[2]:0..16K, Bs[2]:16K..32K; epilogue scratch all 32K
  const int id  = blockIdx.x;                 // 0..1279
  const int w   = (id & 7)*160 + (id >> 3);   // XCD-local bijection
  const int col = w & 7;
  const int ru  = w >> 3;                     // 0..159
  const int row = ru % 80;
  const int br  = ru / 80;

  const unsigned char* A  = A_  + (size_t)br*NPAD2*FDIM;
  const unsigned char* Bt = Bt_ + (size_t)br*FDIM*FDIM;
  const float* bg = br ? bg1 : bg0;
  const int* bstart = bstart_ + br*(BGR+1);
  float* pool = pool_ + br*BGR*FDIM;

  const int row0 = row*128, col0 = col*128;
  const int tid  = threadIdx.x;
  const int lane = tid & 63, wave = tid >> 6;
  const int wm = wave >> 1, wn = wave & 1;
  const int lr = lane >> 2;       // 0..15 row within 16-row staging group
  const int ls = lane & 3;        // linear 16B slot within 64B row

  f32x4 acc[4][4] = {};

  auto stage = [&](int buf, int k0){
    char* Asb = smem + buf*8192;
    char* Bsb = smem + 16384 + buf*8192;
    #pragma unroll
    for (int j = 0; j < 2; ++j){
      const int r0 = wave*32 + j*16;
      const int ra = r0 + lr;
      const int sa = ls ^ ((ra >> 1) & 3);    // pre-swizzled 16B slot
      __builtin_amdgcn_global_load_lds(
        (const __attribute__((address_space(1))) void*)(A + (size_t)(row0+ra)*FDIM + k0 + sa*16),
        (__attribute__((address_space(3))) void*)(Asb + r0*64), 16, 0, 0);
      __builtin_amdgcn_global_load_lds(
        (const __attribute__((address_space(1))) void*)(Bt + (size_t)(col0+ra)*FDIM + k0 + sa*16),
        (__attribute__((address_space(3))) void*)(Bsb + r0*64), 16, 0, 0);
    }
  };

  auto compute = [&](int buf){
    const char* Asb = smem + buf*8192;
    const char* Bsb = smem + 16384 + buf*8192;
    long2v af[4], bf[4];
    const int s = lane >> 4;        // 0..3 = phys slot this lane consumes
    #pragma unroll
    for (int i = 0; i < 4; ++i){
      const int rA = wm*64 + i*16 + (lane & 15);
      af[i] = *(const long2v*)(Asb + rA*64 + ((s ^ ((rA>>1)&3))<<4));
      const int rB = wn*64 + i*16 + (lane & 15);
      bf[i] = *(const long2v*)(Bsb + rB*64 + ((s ^ ((rB>>1)&3))<<4));
    }
    #pragma unroll
    for (int mi = 0; mi < 4; ++mi)
      #pragma unroll
      for (int ni = 0; ni < 4; ++ni){
        acc[mi][ni] = __builtin_amdgcn_mfma_f32_16x16x32_fp8_fp8(af[mi][0], bf[ni][0], acc[mi][ni], 0, 0, 0);
        acc[mi][ni] = __builtin_amdgcn_mfma_f32_16x16x32_fp8_fp8(af[mi][1], bf[ni][1], acc[mi][ni], 0, 0, 0);
      }
  };

  stage(0, 0);                                 // 4 loads in flight
  #pragma unroll 2
  for (int ks = 0; ks < 16; ++ks){
    if (ks < 15){
      stage((ks+1)&1, (ks+1)*64);              // +4 -> 8 in flight
      asm volatile("s_waitcnt vmcnt(4)" ::: "memory");   // current tile landed
    } else {
      asm volatile("s_waitcnt vmcnt(0)" ::: "memory");
    }
    __builtin_amdgcn_s_barrier();              // next tile's loads stay in flight
    compute(ks&1);
    __builtin_amdgcn_s_barrier();              // reads done before overwrite
  }
  __syncthreads();   // drain before scratch overwrite

  // write output tile (f16, post bias+lrelu; 0 for pad rows) into 32KB scratch
  _Float16* sc = (_Float16*)smem;
  float bcol[4];
  #pragma unroll
  for (int ni = 0; ni < 4; ++ni) bcol[ni] = bg[col0 + wn*64 + ni*16 + (lane & 15)];
  #pragma unroll
  for (int mi = 0; mi < 4; ++mi){
    #pragma unroll
    for (int j = 0; j < 4; ++j){
      const int lrow = wm*64 + mi*16 + (lane>>4)*4 + j;
      const int valid = (row0 + lrow) < NNODES;
      #pragma unroll
      for (int ni = 0; ni < 4; ++ni){
        const int lcol = wn*64 + ni*16 + (lane & 15);
        sc[lrow*128 + lcol] = valid ? (_Float16)lrelu(acc[mi][ni][j] + bcol[ni]) : (_Float16)0.f;
      }
    }
  }
  __syncthreads();

  // per-column batch-segment sums: thread t owns col c = t&127, half h = t>>7
  {
    const int c = tid & 127, h = tid >> 7;
    const int base = row0 + h*64;
    int rmax = NNODES - base; if (rmax > 64) rmax = 64;
    if (rmax > 0){
      int b = 0;
      while (bstart[b+1] <= base) ++b;
      int bs_next = bstart[b+1];
      float sum = 0.f;
      for (int r = 0; r < rmax; ++r){
        const int grow = base + r;
        while (grow >= bs_next){
          atomicAdd(&pool[b*FDIM + col0 + c], sum);
          sum = 0.f; ++b; bs_next = bstart[b+1];
        }
        sum += (float)sc[(h*64 + r)*128 + c];
      }
      atomicAdd(&pool[b*FDIM + col0 + c], sum);
    }
  }
}

// ---- pf GEMV on pool SUMS; grid (32,2), blk 512 ----
__global__ __launch_bounds__(512) void k_pf(const float* __restrict__ pool_,
                                            const float* __restrict__ W0,
                                            const float* __restrict__ W1,
                                            const float* __restrict__ bias0,
                                            const float* __restrict__ bias1,
                                            const int* __restrict__ bstart_,
                                            float* __restrict__ x12){
  __shared__ float red[512];
  const int br = blockIdx.y, b = blockIdx.x, t = threadIdx.x;
  const int d = t & 127, kq = t >> 7;
  const float* W = (br ? W1 : W0) + (size_t)kq*256*DDIM + d;
  const float* pp = pool_ + (size_t)(br*BGR + b)*FDIM + kq*256;
  float acc = 0.f;
  #pragma unroll 4
  for (int kk = 0; kk < 256; kk += 4){
    const float4 pv = *(const float4*)(pp + kk);
    acc += pv.x * W[(kk  )*DDIM] + pv.y * W[(kk+1)*DDIM]
         + pv.z * W[(kk+2)*DDIM] + pv.w * W[(kk+3)*DDIM];
  }
  red[t] = acc;
  __syncthreads();
  if (t < 128){
    const int* bstart = bstart_ + br*(BGR+1);
    const int cntn = bstart[b+1] - bstart[b];
    const float inv = 1.0f / fmaxf((float)cntn, 1.0f);
    float a = (red[t] + red[t+128] + red[t+256] + red[t+384]) * inv + (br ? bias1 : bias0)[t];
    x12[((size_t)br*BGR + b)*DDIM + t] = lrelu(a);
  }
}

// ---- head: masif-finish + fc1 -> fc2 -> final sigmoid; grid 32, blk 256 ----
__global__ __launch_bounds__(256) void k_head(const float* __restrict__ x12,
                                              const float* __restrict__ Wfc1, const float* __restrict__ bfc1,
                                              const float* __restrict__ Wfc2, const float* __restrict__ bfc2,
                                              const float* __restrict__ spart, const float* __restrict__ fpart,
                                              const float* __restrict__ sw1, const float* __restrict__ sb1,
                                              const float* __restrict__ fw1, const float* __restrict__ fb1,
                                              const float* __restrict__ sw2, const float* __restrict__ sb2,
                                              const float* __restrict__ fw2, const float* __restrict__ fb2,
                                              const float* __restrict__ Wm1, const float* __restrict__ bm1,
                                              const float* __restrict__ Wm2, const float* __restrict__ bm2,
                                              const float* __restrict__ Wout, const float* __restrict__ bout,
                                              float* __restrict__ out){
  __shared__ float sf[LLEN];
  __shared__ float w80[80];
  __shared__ float mm[2][64];
  __shared__ float xf[256];
  __shared__ float xc[64];
  __shared__ float red[192];
  const int b = blockIdx.x, t = threadIdx.x;

  // masif finish per branch
  #pragma unroll
  for (int br = 0; br < 2; ++br){
    const float swv = (br ? sw2 : sw1)[0], sbv = (br ? sb2 : sb1)[0];
    const float fwv = (br ? fw2 : fw1)[0], fbv = (br ? fb2 : fb1)[0];
    const float* Wm = br ? Wm2 : Wm1;
    const float* bm = br ? bm2 : bm1;
    const float* sp = spart + ((size_t)br*BGR + b)*4*LLEN;
    const float* fp = fpart + ((size_t)br*BGR + b)*4*LLEN;
    for (int l = t; l < LLEN; l += 256){
      float sm = sp[l] + sp[LLEN + l] + sp[2*LLEN + l] + sp[3*LLEN + l];
      float fm = fp[l] + fp[LLEN + l] + fp[2*LLEN + l] + fp[3*LLEN + l];
      sm = fmaxf(sm*(1.0f/16.0f)*swv + sbv, 0.f);
      fm = fmaxf(fm*(1.0f/16.0f)*fwv + fbv, 0.f);
      sf[l] = sm + fm;
    }
    __syncthreads();
    if (t < 80){
      float a = 0.f;
      for (int j = 0; j < 10; ++j) a += sf[t*10 + j];
      w80[t] = a * 0.05f;
    }
    __syncthreads();
    if (t < 64){
      float a = bm[t];
      for (int k = 0; k < 80; ++k) a += w80[k] * Wm[k*64 + t];
      mm[br][t] = a;
    }
    __syncthreads();   // before sf overwrite next iteration
  }

  const float* xin1 = x12 + (size_t)b*DDIM;
  const float* xin2 = x12 + (size_t)(BGR + b)*DDIM;
  float acc = bfc1[t];
  for (int k = 0; k < 128; ++k) acc += xin1[k] * Wfc1[k*256 + t];
  for (int k = 0; k < 128; ++k) acc += xin2[k] * Wfc1[(128+k)*256 + t];
  xf[t] = lrelu(acc);
  __syncthreads();
  if (t < 64){
    float a = bfc2[t];
    for (int k = 0; k < 256; ++k) a += xf[k] * Wfc2[k*64 + t];
    xc[t] = lrelu(a);
  }
  __syncthreads();
  if (t < 192){
    float v;
    if (t < 64)       v = xc[t] * Wout[t];
    else if (t < 128) v = mm[0][t-64] * Wout[t];
    else              v = mm[1][t-128] * Wout[t];
    red[t] = v;
  }
  __syncthreads();
  if (t == 0){
    float a = bout[0];
    for (int i = 0; i < 192; ++i) a += red[i];
    out[b] = 1.0f / (1.0f + expf(-a));
  }
}

extern "C" void kernel_launch(void* const* d_in, const int* in_sizes, int n_in,
                              void* d_out, int out_size, void* d_ws, size_t ws_size,
                              hipStream_t stream){
  const float* pro1_x = (const float*)d_in[0];
  const int*   ei1    = (const int*)d_in[1];
  const int*   batch1 = (const int*)d_in[2];
  const float* pro2_x = (const float*)d_in[3];
  const int*   ei2    = (const int*)d_in[4];
  const int*   batch2 = (const int*)d_in[5];
  const float* mas1_s = (const float*)d_in[6];
  const float* mas1_f = (const float*)d_in[7];
  const float* mas2_s = (const float*)d_in[8];
  const float* mas2_f = (const float*)d_in[9];
  const float* W_g1 = (const float*)d_in[10]; const float* b_g1 = (const float*)d_in[11];
  const float* W_g2 = (const float*)d_in[12]; const float* b_g2 = (const float*)d_in[13];
  const float* W_pf1= (const float*)d_in[14]; const float* b_pf1= (const float*)d_in[15];
  const float* W_pf2= (const float*)d_in[16]; const float* b_pf2= (const float*)d_in[17];
  const float* W_fc1= (const float*)d_in[18]; const float* b_fc1= (const float*)d_in[19];
  const float* W_fc2= (const float*)d_in[20]; const float* b_fc2= (const float*)d_in[21];
  const float* cs1w = (const float*)d_in[22]; const float* cs1b = (const float*)d_in[23];
  const float* cf1w = (const float*)d_in[24]; const float* cf1b = (const float*)d_in[25];
  const float* cs2w = (const float*)d_in[26]; const float* cs2b = (const float*)d_in[27];
  const float* cf2w = (const float*)d_in[28]; const float* cf2b = (const float*)d_in[29];
  const float* W_m1 = (const float*)d_in[30]; const float* b_m1 = (const float*)d_in[31];
  const float* W_m2 = (const float*)d_in[32]; const float* b_m2 = (const float*)d_in[33];
  const float* W_out= (const float*)d_in[34]; const float* b_out= (const float*)d_in[35];
  float* out = (float*)d_out;
  (void)in_sizes; (void)n_in; (void)out_size; (void)ws_size;

  char* p = (char*)d_ws;
  auto alloc = [&](size_t bytes)->char*{ char* r = p; p += (bytes + 255) & ~(size_t)255; return r; };
  int*   cntcur = (int*)alloc((size_t)4*NNODES*4);     // cnt, cursor (zeroed)
  float* pool   = (float*)alloc((size_t)2*BGR*FDIM*4); // pool sums (zeroed, adjacent)
  int*   cnt    = cntcur;
  int*   cursor = cntcur + 2*NNODES;
  unsigned char* xs8 = (unsigned char*)alloc((size_t)2*NNODES*FDIM);   // fp8 xs (linear)
  unsigned char* xa8 = (unsigned char*)alloc((size_t)2*NPAD2*FDIM);    // fp8 xa (unit-permuted)
  unsigned char* Wt8 = (unsigned char*)alloc((size_t)2*FDIM*FDIM);     // fp8 W^T (unit-permuted)
  float* dinv = (float*)alloc((size_t)2*NNODES*4);
  int*   rowstart = (int*)alloc((size_t)2*(NNODES+1)*4);
  int*   csr  = (int*)alloc((size_t)2*NEDGES*4);
  int*   bstart = (int*)alloc((size_t)2*(BGR+1)*4);
  float* x12  = (float*)alloc((size_t)2*BGR*DDIM*4);
  float* spart = (float*)alloc((size_t)2*BGR*4*LLEN*4);
  float* fpart = (float*)alloc((size_t)2*BGR*4*LLEN*4);

  // zero cnt+cursor+pool in one DMA (adjacent in the arena)
  hipMemsetAsync(cntcur, 0, (size_t)4*NNODES*4 + (size_t)2*BGR*FDIM*4, stream);
  k_deg<<<NE_BLK, 256, 0, stream>>>(ei1, ei2, cnt);
  k_scan<<<2, 1024, 0, stream>>>(cnt, rowstart, dinv, batch1, batch2, bstart);
  k_misc<<<MAS_BLK + NE_BLK + 2048 + 2*NNODES, 256, 0, stream>>>(
      ei1, ei2, rowstart, cursor, csr,
      pro1_x, pro2_x, dinv, xs8,
      W_g1, W_g2, Wt8,
      mas1_s, mas1_f, mas2_s, mas2_f,
      spart, fpart);
  k_gath<<<dim3(NPAD2/2, 2), 256, 0, stream>>>(xs8, rowstart, csr, dinv, xa8);
  k_gemm<<<1280, 256, 0, stream>>>(xa8, Wt8, b_g1, b_g2, bstart, pool);
  k_pf<<<dim3(BGR, 2), 512, 0, stream>>>(pool, W_pf1, W_pf2, b_pf1, b_pf2, bstart, x12);
  k_head<<<BGR, 256, 0, stream>>>(x12, W_fc1, b_fc1, W_fc2, b_fc2,
                                  spart, fpart,
                                  cs1w, cs1b, cf1w, cf1b,
                                  cs2w, cs2b, cf2w, cf2b,
                                  W_m1, b_m1, W_m2, b_m2,
                                  W_out, b_out, out);
}